// Round 4
// baseline (199.923 us; speedup 1.0000x reference)
//
#include <hip/hip_runtime.h>
#include <math.h>

#define BATCH 8
#define SEQ   1024
#define HID_  768
#define HEADS 12
#define LORA  256
#define HDIM  64

// scale = HID ** -0.5 ; folded with log2(e) for exp2-based softmax
#define SCALE      0.03608439182435161f
#define SCALE_LOG2 0.05205863235888918f   // SCALE * 1.4426950408889634

typedef _Float16 f16_t;
typedef _Float16 f16x2 __attribute__((ext_vector_type(2)));
typedef _Float16 f16x4 __attribute__((ext_vector_type(4)));
typedef _Float16 f16x8 __attribute__((ext_vector_type(8)));
typedef float    f32x4 __attribute__((ext_vector_type(4)));

// async global->LDS, 16B per lane, LDS dest = uniform base + lane*16
#define GLD16(g, l) __builtin_amdgcn_global_load_lds( \
    (const __attribute__((address_space(1))) void*)(g), \
    (__attribute__((address_space(3))) void*)(l), 16, 0, 0)

// XOR swizzle for 64-elem f16 rows (8 chunks of 8): chunk c of row r at c^(r&7).
#define SW(c, r) ((((c) ^ ((r) & 7)) << 3))

#define N4_HS (BATCH * SEQ * HID_ / 4)

// ---------------------------------------------------------------------------
// prep: blocks [0,288) fuse W[h] = Wa.Wt -> fp16; blocks [288,1312) cvt hs.
// Fused into one launch to remove one kernel-boundary gap.
// ---------------------------------------------------------------------------
__global__ __launch_bounds__(256) void prep_kernel(
    const float4* __restrict__ hs, const float* __restrict__ Wt,
    const float* __restrict__ Wa, f16x4* __restrict__ hs_f,
    f16_t* __restrict__ w_f)
{
    __shared__ float s_a[64][68];   // Wa chunk [e][l], +4 pad
    __shared__ float s_b[64][36];   // Wt chunk [l][d0+32], +4 pad

    const int tid = threadIdx.x;

    if (blockIdx.x >= 288) {        // ---- hs fp32 -> fp16 ----
        int i0 = (blockIdx.x - 288) * 256 + tid;
        int stride = (gridDim.x - 288) * 256;
        for (int i = i0; i < N4_HS; i += stride) {
            float4 v = hs[i];
            f16x4 o = {(f16_t)v.x, (f16_t)v.y, (f16_t)v.z, (f16_t)v.w};
            hs_f[i] = o;
        }
        return;
    }

    // ---- W[h] = Wa[h] (64x256) . Wt[h] (256x768), fp32 accumulate ----
    const int bid = blockIdx.x;
    const int h   = bid / 24;
    const int d0  = (bid % 24) * 32;
    const int ty  = tid >> 4;
    const int tx  = tid & 15;

    const float* wa_g = Wa + (size_t)h * HDIM * LORA;
    const float* wt_g = Wt + (size_t)h * LORA * HID_;

    float acc[4][2] = {{0.f, 0.f}, {0.f, 0.f}, {0.f, 0.f}, {0.f, 0.f}};

    for (int kc = 0; kc < 4; ++kc) {
        const int l0 = kc * 64;
        if (kc) __syncthreads();
        #pragma unroll
        for (int k = 0; k < 4; ++k) {
            int u = tid + k * 256;
            int r = u >> 4, c4 = (u & 15) * 4;
            *(float4*)&s_a[r][c4] = *(const float4*)&wa_g[(size_t)r * LORA + l0 + c4];
        }
        #pragma unroll
        for (int k = 0; k < 2; ++k) {
            int u = tid + k * 256;
            int r = u >> 3, c4 = (u & 7) * 4;
            *(float4*)&s_b[r][c4] = *(const float4*)&wt_g[(size_t)(l0 + r) * HID_ + d0 + c4];
        }
        __syncthreads();

        #pragma unroll 8
        for (int l = 0; l < 64; ++l) {
            float a0 = s_a[ty * 4 + 0][l];
            float a1 = s_a[ty * 4 + 1][l];
            float a2 = s_a[ty * 4 + 2][l];
            float a3 = s_a[ty * 4 + 3][l];
            float b0 = s_b[l][tx * 2 + 0];
            float b1 = s_b[l][tx * 2 + 1];
            acc[0][0] = fmaf(a0, b0, acc[0][0]); acc[0][1] = fmaf(a0, b1, acc[0][1]);
            acc[1][0] = fmaf(a1, b0, acc[1][0]); acc[1][1] = fmaf(a1, b1, acc[1][1]);
            acc[2][0] = fmaf(a2, b0, acc[2][0]); acc[2][1] = fmaf(a2, b1, acc[2][1]);
            acc[3][0] = fmaf(a3, b0, acc[3][0]); acc[3][1] = fmaf(a3, b1, acc[3][1]);
        }
    }

    f16_t* wg = w_f + (size_t)h * HDIM * HID_;
    #pragma unroll
    for (int i = 0; i < 4; ++i) {
        int e = ty * 4 + i;
        f16x2 o = {(f16_t)acc[i][0], (f16_t)acc[i][1]};
        *(f16x2*)&wg[(size_t)e * HID_ + d0 + tx * 2] = o;
    }
}

// ---------------------------------------------------------------------------
// t = hs_f . W[h]^T : per block 128 n-rows x 64 e-cols, K = 768.
// T3 2-phase double-buffered LDS pipeline (unchanged from round 2).
// ---------------------------------------------------------------------------
__global__ __launch_bounds__(256, 3) void gemm_t(
    const f16_t* __restrict__ hs_f, const f16_t* __restrict__ w_f,
    f16_t* __restrict__ t_f, f16_t* __restrict__ tT_f)
{
    __shared__ __attribute__((aligned(16))) char smem[49152];
    f16_t* s_hs = (f16_t*)smem;              // [2][128][64] A tiles
    f16_t* s_wt = (f16_t*)(smem + 32768);    // [2][64][64]  W tiles
    f16_t* s_ob = (f16_t*)smem;              // [128][72]    epilogue alias

    const int bid   = blockIdx.x;
    const int ntile = bid & 7;               // hs-tile sharers (12 heads) on one XCD
    const int h     = (bid >> 3) % HEADS;
    const int b     = bid / (8 * HEADS);
    const int n0    = ntile * 128;
    const int tid   = threadIdx.x;
    const int w     = tid >> 6;
    const int lane  = tid & 63;
    const int q     = lane >> 4;
    const int mr    = lane & 15;
    const int lrow  = lane >> 3;
    const int gswz  = (((lane & 7) ^ lrow) & 7) * 8;

    const f16_t* hs_g = hs_f + ((size_t)b * SEQ + n0) * HID_;
    const f16_t* w_g  = w_f + (size_t)h * HDIM * HID_;

    const f32x4 z4 = {0.f, 0.f, 0.f, 0.f};
    f32x4 acc[2][4];
    #pragma unroll
    for (int mt = 0; mt < 2; ++mt)
        #pragma unroll
        for (int et = 0; et < 4; ++et) acc[mt][et] = z4;

    auto STAGE = [&](int buf, int rd) {
        const int k0 = rd * 64;
        f16_t* sa = s_hs + buf * (128 * 64);
        f16_t* sb = s_wt + buf * (64 * 64);
        #pragma unroll
        for (int tt = 0; tt < 4; ++tt) {
            int r0 = w * 32 + tt * 8;
            GLD16(hs_g + (size_t)(r0 + lrow) * HID_ + k0 + gswz, sa + r0 * 64);
        }
        #pragma unroll
        for (int tt = 0; tt < 2; ++tt) {
            int r0 = w * 16 + tt * 8;
            GLD16(w_g + (size_t)(r0 + lrow) * HID_ + k0 + gswz, sb + r0 * 64);
        }
    };

    auto COMPUTE = [&](int buf) {
        const f16_t* sa = s_hs + buf * (128 * 64);
        const f16_t* sb = s_wt + buf * (64 * 64);
        #pragma unroll
        for (int ks = 0; ks < 2; ++ks) {
            f16x8 a_[2], b_[4];
            #pragma unroll
            for (int mt = 0; mt < 2; ++mt)
                a_[mt] = *(const f16x8*)(sa + (w * 32 + mt * 16 + mr) * 64 + SW(ks * 4 + q, mr));
            #pragma unroll
            for (int et = 0; et < 4; ++et)
                b_[et] = *(const f16x8*)(sb + (et * 16 + mr) * 64 + SW(ks * 4 + q, mr));
            #pragma unroll
            for (int mt = 0; mt < 2; ++mt)
                #pragma unroll
                for (int et = 0; et < 4; ++et)
                    acc[mt][et] = __builtin_amdgcn_mfma_f32_16x16x32_f16(a_[mt], b_[et], acc[mt][et], 0, 0, 0);
        }
    };

    STAGE(0, 0);
    __syncthreads();
    #pragma unroll 1
    for (int rr = 0; rr < 6; ++rr) {
        STAGE(1, 2 * rr + 1);
        COMPUTE(0);
        __syncthreads();
        if (rr < 5) STAGE(0, 2 * rr + 2);
        COMPUTE(1);
        __syncthreads();
    }

    // ---- epilogue: acc -> LDS tile -> vectorized t and tT writes ----
    #pragma unroll
    for (int mt = 0; mt < 2; ++mt) {
        #pragma unroll
        for (int et = 0; et < 4; ++et) {
            #pragma unroll
            for (int r = 0; r < 4; ++r) {
                int row = w * 32 + mt * 16 + q * 4 + r;
                int col = et * 16 + mr;
                s_ob[row * 72 + col] = (f16_t)acc[mt][et][r];
            }
        }
    }
    __syncthreads();

    f16_t* tg = t_f + (((size_t)b * HEADS + h) * SEQ + n0) * HDIM;
    #pragma unroll
    for (int k = 0; k < 4; ++k) {
        int u = tid + k * 256;
        int row = u >> 3, c8 = (u & 7) * 8;
        *(f16x8*)&tg[row * 64 + c8] = *(const f16x8*)&s_ob[row * 72 + c8];
    }
    f16_t* tTg = tT_f + ((size_t)b * HEADS + h) * SEQ * HDIM;
    #pragma unroll
    for (int k = 0; k < 4; ++k) {
        int u = tid + k * 256;
        int e = u & 63, n8 = (u >> 6) * 8;
        f16x8 v;
        #pragma unroll
        for (int j = 0; j < 8; ++j) v[j] = s_ob[(n8 + j) * 72 + e];
        *(f16x8*)&tTg[(size_t)e * SEQ + n0 + n8] = v;
    }
}

// ---------------------------------------------------------------------------
// Flash attention v3:
//  - XCD-grouped decode: bh = bid % 96 (96 % 8 == 0 -> the 8 i-tile blocks
//    sharing one (b,h)'s K/V all land on one XCD; K/V stays L2-resident).
//  - K/V double-buffered (T3 2-phase): stage j+1 under compute of j,
//    one barrier per tile (17 total vs 32).
//  - s_p: stride-64 + chunk-XOR swizzle (was stride-72, 8-way conflicts).
//  - cvt_pkrtz for P f32->f16 pack (bit_cast to f16x2: builtin returns __fp16x2).
// LDS 48 KB -> 3 blocks/CU. grid 768, block 256.
// ---------------------------------------------------------------------------
__global__ __launch_bounds__(256, 3) void attn_mfma(
    const f16_t* __restrict__ t_f, const f16_t* __restrict__ tT_f,
    const int* __restrict__ mask, float* __restrict__ out)
{
    __shared__ __attribute__((aligned(16))) char smem[49152];
    f16_t* s_k = (f16_t*)smem;              // [2][64 j][64 e] swizzled
    f16_t* s_v = (f16_t*)(smem + 16384);    // [2][64 e][64 j] swizzled
    f16_t* s_p = (f16_t*)(smem + 32768);    // [128 i][64] chunk-XOR swizzled
    float* s_m = (float*)smem;              // merge alias (2*64*68 f32 = 34816 B)

    const int bid  = blockIdx.x;
    const int bh   = bid % (BATCH * HEADS);  // same-(b,h) blocks: bids stride 96 -> same XCD
    const int it   = bid / (BATCH * HEADS);
    const int h    = bh % HEADS;
    const int b    = bh / HEADS;
    const int i0   = it * 128;
    const int tid  = threadIdx.x;
    const int w    = tid >> 6;
    const int lane = tid & 63;
    const int q    = lane >> 4;
    const int mr   = lane & 15;
    const int lrow = lane >> 3;
    const int gswz = (((lane & 7) ^ lrow) & 7) * 8;
    const int ih   = w >> 1;                // i-half (64 rows)
    const int jh   = w & 1;                 // j-half (32 cols)

    const size_t bh_off = ((size_t)b * HEADS + h) * SEQ * HDIM;
    const f16_t* th = t_f + bh_off;   // [1024][64]
    const f16_t* vh = tT_f + bh_off;  // [64][1024]
    const int* mk = mask + (size_t)b * SEQ;

    // Q fragments, rows i = i0 + ih*64 + mt*16 + mr, pre-scaled by SCALE*log2e
    f16x8 qf[4][2];
    #pragma unroll
    for (int mt = 0; mt < 4; ++mt)
        #pragma unroll
        for (int ks = 0; ks < 2; ++ks) {
            f16x8 v = *(const f16x8*)(th + (size_t)(i0 + ih * 64 + mt * 16 + mr) * 64
                                      + ks * 32 + q * 8);
            #pragma unroll
            for (int j = 0; j < 8; ++j) v[j] = v[j] * (f16_t)SCALE_LOG2;
            qf[mt][ks] = v;
        }

    const f32x4 z4 = {0.f, 0.f, 0.f, 0.f};
    float l_[4] = {0.f, 0.f, 0.f, 0.f};
    f32x4 oT[4][4];
    #pragma unroll
    for (int mt = 0; mt < 4; ++mt)
        #pragma unroll
        for (int et = 0; et < 4; ++et) oT[mt][et] = z4;

    auto STAGE = [&](int buf, int j0) {
        f16_t* dk = s_k + buf * 4096;
        f16_t* dv = s_v + buf * 4096;
        #pragma unroll
        for (int t2 = 0; t2 < 2; ++t2) {
            int r0 = w * 16 + t2 * 8;
            GLD16(th + (size_t)(j0 + r0 + lrow) * 64 + gswz,  dk + r0 * 64);
            GLD16(vh + (size_t)(r0 + lrow) * SEQ + j0 + gswz, dv + r0 * 64);
        }
    };

    auto PROCESS = [&](int buf, int j0) {
        const f16_t* sk = s_k + buf * 4096;
        const f16_t* sv = s_v + buf * 4096;
        // ---- S^T over the wave's j-half; softmax immediately per jt ----
        #pragma unroll
        for (int jt = 0; jt < 2; ++jt) {
            f32x4 st[4] = {z4, z4, z4, z4};
            #pragma unroll
            for (int ks = 0; ks < 2; ++ks) {
                f16x8 kf = *(const f16x8*)(sk + (jh * 32 + jt * 16 + mr) * 64 + SW(ks * 4 + q, mr));
                #pragma unroll
                for (int mt = 0; mt < 4; ++mt)
                    st[mt] = __builtin_amdgcn_mfma_f32_16x16x32_f16(kf, qf[mt][ks], st[mt], 0, 0, 0);
            }
            int4 mv = *(const int4*)(mk + j0 + jh * 32 + jt * 16 + q * 4);
            const int c8w = (jh * 4 + jt * 2 + (q >> 1)) ^ (mr & 7);
            #pragma unroll
            for (int mt = 0; mt < 4; ++mt) {
                float p0 = (mv.x == 0) ? 0.f : __builtin_amdgcn_exp2f(st[mt][0]);
                float p1 = (mv.y == 0) ? 0.f : __builtin_amdgcn_exp2f(st[mt][1]);
                float p2 = (mv.z == 0) ? 0.f : __builtin_amdgcn_exp2f(st[mt][2]);
                float p3 = (mv.w == 0) ? 0.f : __builtin_amdgcn_exp2f(st[mt][3]);
                l_[mt] += (p0 + p1) + (p2 + p3);
                f16x2 lo = __builtin_bit_cast(f16x2, __builtin_amdgcn_cvt_pkrtz(p0, p1));
                f16x2 hi = __builtin_bit_cast(f16x2, __builtin_amdgcn_cvt_pkrtz(p2, p3));
                f16x4 u4 = __builtin_shufflevector(lo, hi, 0, 1, 2, 3);
                int prow = ih * 64 + mt * 16 + mr;
                *(f16x4*)&s_p[prow * 64 + (c8w << 3) + (q & 1) * 4] = u4;
            }
        }
        // ---- O^T += V^T . P^T over this wave's j-half (intra-wave P) ----
        f16x8 pf[4];
        const int c8r = (jh * 4 + q) ^ (mr & 7);
        #pragma unroll
        for (int mt = 0; mt < 4; ++mt)
            pf[mt] = *(const f16x8*)(s_p + (ih * 64 + mt * 16 + mr) * 64 + (c8r << 3));
        #pragma unroll
        for (int et = 0; et < 4; ++et) {
            f16x8 vv = *(const f16x8*)(sv + (et * 16 + mr) * 64 + SW(jh * 4 + q, mr));
            #pragma unroll
            for (int mt = 0; mt < 4; ++mt)
                oT[mt][et] = __builtin_amdgcn_mfma_f32_16x16x32_f16(vv, pf[mt], oT[mt][et], 0, 0, 0);
        }
    };

    STAGE(0, 0);
    __syncthreads();
    #pragma unroll 1
    for (int rr = 0; rr < 8; ++rr) {
        STAGE(1, rr * 128 + 64);
        PROCESS(0, rr * 128);
        __syncthreads();
        if (rr < 7) STAGE(0, rr * 128 + 128);
        PROCESS(1, rr * 128 + 64);
        __syncthreads();
    }

    // ---- in-wave ell reduction over q-lanes ----
    #pragma unroll
    for (int mt = 0; mt < 4; ++mt) {
        l_[mt] += __shfl_xor(l_[mt], 16);
        l_[mt] += __shfl_xor(l_[mt], 32);
    }

    // ---- cross-wave merge (j-half pairs share i-rows) via LDS ----
    if (jh == 1) {
        float* dst = s_m + ((size_t)ih * 64 + lane) * 68;
        #pragma unroll
        for (int mt = 0; mt < 4; ++mt) {
            #pragma unroll
            for (int et = 0; et < 4; ++et)
                *(f32x4*)&dst[(mt * 4 + et) * 4] = oT[mt][et];
            dst[64 + mt] = l_[mt];
        }
    }
    __syncthreads();
    if (jh == 0) {
        const float* src = s_m + ((size_t)ih * 64 + lane) * 68;
        #pragma unroll
        for (int mt = 0; mt < 4; ++mt) {
            float lt = l_[mt] + src[64 + mt];
            float inv = (lt > 0.f) ? 1.f / lt : 0.f;
            int n = i0 + ih * 64 + mt * 16 + mr;
            #pragma unroll
            for (int et = 0; et < 4; ++et) {
                f32x4 o2 = *(const f32x4*)&src[(mt * 4 + et) * 4];
                float4 v = {(oT[mt][et][0] + o2[0]) * inv, (oT[mt][et][1] + o2[1]) * inv,
                            (oT[mt][et][2] + o2[2]) * inv, (oT[mt][et][3] + o2[3]) * inv};
                *(float4*)&out[((size_t)b * SEQ + n) * (HEADS * HDIM) + h * HDIM + et * 16 + q * 4] = v;
            }
        }
    }
}

extern "C" void kernel_launch(void* const* d_in, const int* in_sizes, int n_in,
                              void* d_out, int out_size, void* d_ws, size_t ws_size,
                              hipStream_t stream) {
    const float* hs   = (const float*)d_in[0];
    const int*   mask = (const int*)d_in[1];
    const float* Wt   = (const float*)d_in[2];
    const float* Wa   = (const float*)d_in[3];
    float* out = (float*)d_out;

    // workspace layout (38,928,384 B total):
    char* ws = (char*)d_ws;
    f16_t* t_f  = (f16_t*)ws;                  // 12.58 MB
    f16_t* tT_f = (f16_t*)(ws + 12582912);     // 12.58 MB
    f16_t* hs_f = (f16_t*)(ws + 25165824);     // 12.58 MB
    f16_t* w_f  = (f16_t*)(ws + 37748736);     //  1.18 MB  (fused Wa.Wt, fp16)

    prep_kernel<<<288 + 1024, 256, 0, stream>>>(
        (const float4*)hs, Wt, Wa, (f16x4*)hs_f, w_f);

    gemm_t<<<BATCH * HEADS * (SEQ / 128), 256, 0, stream>>>(hs_f, w_f, t_f, tT_f);

    attn_mfma<<<BATCH * HEADS * (SEQ / 128), 256, 0, stream>>>(
        t_f, tT_f, mask, out);
}

// Round 5
// 148.367 us; speedup vs baseline: 1.3475x; 1.3475x over previous
//
#include <hip/hip_runtime.h>
#include <math.h>

#define BATCH 8
#define SEQ   1024
#define HID_  768
#define HEADS 12
#define LORA  256
#define HDIM  64

// scale = HID ** -0.5 ; folded with log2(e) for exp2-based softmax
#define SCALE      0.03608439182435161f
#define SCALE_LOG2 0.05205863235888918f   // SCALE * 1.4426950408889634

typedef _Float16 f16_t;
typedef _Float16 f16x2 __attribute__((ext_vector_type(2)));
typedef _Float16 f16x4 __attribute__((ext_vector_type(4)));
typedef _Float16 f16x8 __attribute__((ext_vector_type(8)));
typedef float    f32x4 __attribute__((ext_vector_type(4)));

// async global->LDS, 16B per lane, LDS dest = uniform base + lane*16
#define GLD16(g, l) __builtin_amdgcn_global_load_lds( \
    (const __attribute__((address_space(1))) void*)(g), \
    (__attribute__((address_space(3))) void*)(l), 16, 0, 0)

// XOR swizzle for 64-elem f16 rows (8 chunks of 8): chunk c of row r at c^(r&7).
#define SW(c, r) ((((c) ^ ((r) & 7)) << 3))

#define N4_HS (BATCH * SEQ * HID_ / 4)

// ---------------------------------------------------------------------------
// prep: blocks [0,288) fuse W[h] = Wa.Wt -> fp16; blocks [288,1312) cvt hs.
// ---------------------------------------------------------------------------
__global__ __launch_bounds__(256) void prep_kernel(
    const float4* __restrict__ hs, const float* __restrict__ Wt,
    const float* __restrict__ Wa, f16x4* __restrict__ hs_f,
    f16_t* __restrict__ w_f)
{
    __shared__ float s_a[64][68];   // Wa chunk [e][l], +4 pad
    __shared__ float s_b[64][36];   // Wt chunk [l][d0+32], +4 pad

    const int tid = threadIdx.x;

    if (blockIdx.x >= 288) {        // ---- hs fp32 -> fp16 ----
        int i0 = (blockIdx.x - 288) * 256 + tid;
        int stride = (gridDim.x - 288) * 256;
        for (int i = i0; i < N4_HS; i += stride) {
            float4 v = hs[i];
            f16x4 o = {(f16_t)v.x, (f16_t)v.y, (f16_t)v.z, (f16_t)v.w};
            hs_f[i] = o;
        }
        return;
    }

    // ---- W[h] = Wa[h] (64x256) . Wt[h] (256x768), fp32 accumulate ----
    const int bid = blockIdx.x;
    const int h   = bid / 24;
    const int d0  = (bid % 24) * 32;
    const int ty  = tid >> 4;
    const int tx  = tid & 15;

    const float* wa_g = Wa + (size_t)h * HDIM * LORA;
    const float* wt_g = Wt + (size_t)h * LORA * HID_;

    float acc[4][2] = {{0.f, 0.f}, {0.f, 0.f}, {0.f, 0.f}, {0.f, 0.f}};

    for (int kc = 0; kc < 4; ++kc) {
        const int l0 = kc * 64;
        if (kc) __syncthreads();
        #pragma unroll
        for (int k = 0; k < 4; ++k) {
            int u = tid + k * 256;
            int r = u >> 4, c4 = (u & 15) * 4;
            *(float4*)&s_a[r][c4] = *(const float4*)&wa_g[(size_t)r * LORA + l0 + c4];
        }
        #pragma unroll
        for (int k = 0; k < 2; ++k) {
            int u = tid + k * 256;
            int r = u >> 3, c4 = (u & 7) * 4;
            *(float4*)&s_b[r][c4] = *(const float4*)&wt_g[(size_t)(l0 + r) * HID_ + d0 + c4];
        }
        __syncthreads();

        #pragma unroll 8
        for (int l = 0; l < 64; ++l) {
            float a0 = s_a[ty * 4 + 0][l];
            float a1 = s_a[ty * 4 + 1][l];
            float a2 = s_a[ty * 4 + 2][l];
            float a3 = s_a[ty * 4 + 3][l];
            float b0 = s_b[l][tx * 2 + 0];
            float b1 = s_b[l][tx * 2 + 1];
            acc[0][0] = fmaf(a0, b0, acc[0][0]); acc[0][1] = fmaf(a0, b1, acc[0][1]);
            acc[1][0] = fmaf(a1, b0, acc[1][0]); acc[1][1] = fmaf(a1, b1, acc[1][1]);
            acc[2][0] = fmaf(a2, b0, acc[2][0]); acc[2][1] = fmaf(a2, b1, acc[2][1]);
            acc[3][0] = fmaf(a3, b0, acc[3][0]); acc[3][1] = fmaf(a3, b1, acc[3][1]);
        }
    }

    f16_t* wg = w_f + (size_t)h * HDIM * HID_;
    #pragma unroll
    for (int i = 0; i < 4; ++i) {
        int e = ty * 4 + i;
        f16x2 o = {(f16_t)acc[i][0], (f16_t)acc[i][1]};
        *(f16x2*)&wg[(size_t)e * HID_ + d0 + tx * 2] = o;
    }
}

// ---------------------------------------------------------------------------
// t = hs_f . W[h]^T : per block 128 n-rows x 64 e-cols, K = 768.
// T3 2-phase double-buffered LDS pipeline (verified, unchanged).
// ---------------------------------------------------------------------------
__global__ __launch_bounds__(256, 3) void gemm_t(
    const f16_t* __restrict__ hs_f, const f16_t* __restrict__ w_f,
    f16_t* __restrict__ t_f, f16_t* __restrict__ tT_f)
{
    __shared__ __attribute__((aligned(16))) char smem[49152];
    f16_t* s_hs = (f16_t*)smem;              // [2][128][64] A tiles
    f16_t* s_wt = (f16_t*)(smem + 32768);    // [2][64][64]  W tiles
    f16_t* s_ob = (f16_t*)smem;              // [128][72]    epilogue alias

    const int bid   = blockIdx.x;
    const int ntile = bid & 7;               // hs-tile sharers (12 heads) on one XCD
    const int h     = (bid >> 3) % HEADS;
    const int b     = bid / (8 * HEADS);
    const int n0    = ntile * 128;
    const int tid   = threadIdx.x;
    const int w     = tid >> 6;
    const int lane  = tid & 63;
    const int q     = lane >> 4;
    const int mr    = lane & 15;
    const int lrow  = lane >> 3;
    const int gswz  = (((lane & 7) ^ lrow) & 7) * 8;

    const f16_t* hs_g = hs_f + ((size_t)b * SEQ + n0) * HID_;
    const f16_t* w_g  = w_f + (size_t)h * HDIM * HID_;

    const f32x4 z4 = {0.f, 0.f, 0.f, 0.f};
    f32x4 acc[2][4];
    #pragma unroll
    for (int mt = 0; mt < 2; ++mt)
        #pragma unroll
        for (int et = 0; et < 4; ++et) acc[mt][et] = z4;

    auto STAGE = [&](int buf, int rd) {
        const int k0 = rd * 64;
        f16_t* sa = s_hs + buf * (128 * 64);
        f16_t* sb = s_wt + buf * (64 * 64);
        #pragma unroll
        for (int tt = 0; tt < 4; ++tt) {
            int r0 = w * 32 + tt * 8;
            GLD16(hs_g + (size_t)(r0 + lrow) * HID_ + k0 + gswz, sa + r0 * 64);
        }
        #pragma unroll
        for (int tt = 0; tt < 2; ++tt) {
            int r0 = w * 16 + tt * 8;
            GLD16(w_g + (size_t)(r0 + lrow) * HID_ + k0 + gswz, sb + r0 * 64);
        }
    };

    auto COMPUTE = [&](int buf) {
        const f16_t* sa = s_hs + buf * (128 * 64);
        const f16_t* sb = s_wt + buf * (64 * 64);
        #pragma unroll
        for (int ks = 0; ks < 2; ++ks) {
            f16x8 a_[2], b_[4];
            #pragma unroll
            for (int mt = 0; mt < 2; ++mt)
                a_[mt] = *(const f16x8*)(sa + (w * 32 + mt * 16 + mr) * 64 + SW(ks * 4 + q, mr));
            #pragma unroll
            for (int et = 0; et < 4; ++et)
                b_[et] = *(const f16x8*)(sb + (et * 16 + mr) * 64 + SW(ks * 4 + q, mr));
            #pragma unroll
            for (int mt = 0; mt < 2; ++mt)
                #pragma unroll
                for (int et = 0; et < 4; ++et)
                    acc[mt][et] = __builtin_amdgcn_mfma_f32_16x16x32_f16(a_[mt], b_[et], acc[mt][et], 0, 0, 0);
        }
    };

    STAGE(0, 0);
    __syncthreads();
    #pragma unroll 1
    for (int rr = 0; rr < 6; ++rr) {
        STAGE(1, 2 * rr + 1);
        COMPUTE(0);
        __syncthreads();
        if (rr < 5) STAGE(0, 2 * rr + 2);
        COMPUTE(1);
        __syncthreads();
    }

    // ---- epilogue: acc -> LDS tile -> vectorized t and tT writes ----
    #pragma unroll
    for (int mt = 0; mt < 2; ++mt) {
        #pragma unroll
        for (int et = 0; et < 4; ++et) {
            #pragma unroll
            for (int r = 0; r < 4; ++r) {
                int row = w * 32 + mt * 16 + q * 4 + r;
                int col = et * 16 + mr;
                s_ob[row * 72 + col] = (f16_t)acc[mt][et][r];
            }
        }
    }
    __syncthreads();

    f16_t* tg = t_f + (((size_t)b * HEADS + h) * SEQ + n0) * HDIM;
    #pragma unroll
    for (int k = 0; k < 4; ++k) {
        int u = tid + k * 256;
        int row = u >> 3, c8 = (u & 7) * 8;
        *(f16x8*)&tg[row * 64 + c8] = *(const f16x8*)&s_ob[row * 72 + c8];
    }
    f16_t* tTg = tT_f + ((size_t)b * HEADS + h) * SEQ * HDIM;
    #pragma unroll
    for (int k = 0; k < 4; ++k) {
        int u = tid + k * 256;
        int e = u & 63, n8 = (u >> 6) * 8;
        f16x8 v;
        #pragma unroll
        for (int j = 0; j < 8; ++j) v[j] = s_ob[(n8 + j) * 72 + e];
        *(f16x8*)&tTg[(size_t)e * SEQ + n0 + n8] = v;
    }
}

// ---------------------------------------------------------------------------
// Flash attention: round-2 body VERBATIM (single-buffered K/V, stride-72 s_p,
// measured 49.5 us) with ONE change: XCD-grouped decode (bh = bid % 96) so
// the 8 i-tile blocks sharing a (b,h)'s K/V land on one XCD (bid%8 invariant)
// -> per-XCD L2 working set 24 MB -> 3 MB.
// ---------------------------------------------------------------------------
__global__ __launch_bounds__(256, 3) void attn_mfma(
    const f16_t* __restrict__ t_f, const f16_t* __restrict__ tT_f,
    const int* __restrict__ mask, float* __restrict__ out)
{
    __shared__ __attribute__((aligned(16))) char smem[34816];
    f16_t* s_k = (f16_t*)smem;              // [64 j][64 e] swizzled
    f16_t* s_v = (f16_t*)(smem + 8192);     // [64 e][64 j] swizzled
    f16_t* s_p = (f16_t*)(smem + 16384);    // [128 i][72]  plain stride 72
    float* s_m = (float*)smem;              // merge buffer alias (2*64*68 f32)

    const int bid  = blockIdx.x;
    const int bh   = bid % (BATCH * HEADS);  // same-(b,h) blocks: bid stride 96 -> same XCD
    const int it   = bid / (BATCH * HEADS);
    const int h    = bh % HEADS;
    const int b    = bh / HEADS;
    const int i0   = it * 128;
    const int tid  = threadIdx.x;
    const int w    = tid >> 6;
    const int lane = tid & 63;
    const int q    = lane >> 4;
    const int mr   = lane & 15;
    const int lrow = lane >> 3;
    const int gswz = (((lane & 7) ^ lrow) & 7) * 8;
    const int ih   = w >> 1;                // i-half (64 rows)
    const int jh   = w & 1;                 // j-half (32 cols)

    const size_t bh_off = ((size_t)b * HEADS + h) * SEQ * HDIM;
    const f16_t* th = t_f + bh_off;   // [1024][64]
    const f16_t* vh = tT_f + bh_off;  // [64][1024]
    const int* mk = mask + (size_t)b * SEQ;

    // Q fragments, rows i = i0 + ih*64 + mt*16 + mr, pre-scaled by SCALE*log2e
    f16x8 qf[4][2];
    #pragma unroll
    for (int mt = 0; mt < 4; ++mt)
        #pragma unroll
        for (int ks = 0; ks < 2; ++ks) {
            f16x8 v = *(const f16x8*)(th + (size_t)(i0 + ih * 64 + mt * 16 + mr) * 64
                                      + ks * 32 + q * 8);
            #pragma unroll
            for (int j = 0; j < 8; ++j) v[j] = v[j] * (f16_t)SCALE_LOG2;
            qf[mt][ks] = v;
        }

    const f32x4 z4 = {0.f, 0.f, 0.f, 0.f};
    float l_[4] = {0.f, 0.f, 0.f, 0.f};
    f32x4 oT[4][4];
    #pragma unroll
    for (int mt = 0; mt < 4; ++mt)
        #pragma unroll
        for (int et = 0; et < 4; ++et) oT[mt][et] = z4;

    for (int jt6 = 0; jt6 < 16; ++jt6) {
        const int j0 = jt6 * 64;
        __syncthreads();
        #pragma unroll
        for (int t2 = 0; t2 < 2; ++t2) {
            int r0 = w * 16 + t2 * 8;
            GLD16(th + (size_t)(j0 + r0 + lrow) * 64 + gswz,  s_k + r0 * 64);
            GLD16(vh + (size_t)(r0 + lrow) * SEQ + j0 + gswz, s_v + r0 * 64);
        }
        __syncthreads();

        // ---- S^T over the wave's j-half; softmax immediately per jt ----
        #pragma unroll
        for (int jt = 0; jt < 2; ++jt) {
            f32x4 st[4] = {z4, z4, z4, z4};
            #pragma unroll
            for (int ks = 0; ks < 2; ++ks) {
                f16x8 kf = *(const f16x8*)(s_k + (jh * 32 + jt * 16 + mr) * 64 + SW(ks * 4 + q, mr));
                #pragma unroll
                for (int mt = 0; mt < 4; ++mt)
                    st[mt] = __builtin_amdgcn_mfma_f32_16x16x32_f16(kf, qf[mt][ks], st[mt], 0, 0, 0);
            }
            int4 mv = *(const int4*)(mk + j0 + jh * 32 + jt * 16 + q * 4);
            #pragma unroll
            for (int mt = 0; mt < 4; ++mt) {
                float p0 = (mv.x == 0) ? 0.f : __builtin_amdgcn_exp2f(st[mt][0]);
                float p1 = (mv.y == 0) ? 0.f : __builtin_amdgcn_exp2f(st[mt][1]);
                float p2 = (mv.z == 0) ? 0.f : __builtin_amdgcn_exp2f(st[mt][2]);
                float p3 = (mv.w == 0) ? 0.f : __builtin_amdgcn_exp2f(st[mt][3]);
                l_[mt] += (p0 + p1) + (p2 + p3);
                f16x4 u4 = {(f16_t)p0, (f16_t)p1, (f16_t)p2, (f16_t)p3};
                *(f16x4*)&s_p[(ih * 64 + mt * 16 + mr) * 72 + jh * 32 + jt * 16 + q * 4] = u4;
            }
        }

        // ---- O^T += V^T . P^T over this wave's j-half (intra-wave P) ----
        f16x8 pf[4];
        #pragma unroll
        for (int mt = 0; mt < 4; ++mt)
            pf[mt] = *(const f16x8*)(s_p + (ih * 64 + mt * 16 + mr) * 72 + jh * 32 + q * 8);
        #pragma unroll
        for (int et = 0; et < 4; ++et) {
            f16x8 vv = *(const f16x8*)(s_v + (et * 16 + mr) * 64 + SW(jh * 4 + q, mr));
            #pragma unroll
            for (int mt = 0; mt < 4; ++mt)
                oT[mt][et] = __builtin_amdgcn_mfma_f32_16x16x32_f16(vv, pf[mt], oT[mt][et], 0, 0, 0);
        }
    }

    // ---- in-wave ell reduction over q-lanes ----
    #pragma unroll
    for (int mt = 0; mt < 4; ++mt) {
        l_[mt] += __shfl_xor(l_[mt], 16);
        l_[mt] += __shfl_xor(l_[mt], 32);
    }

    // ---- cross-wave merge (j-half pairs share i-rows) via LDS ----
    __syncthreads();                          // everyone done with s_k/s_v/s_p
    if (jh == 1) {
        float* dst = s_m + ((size_t)ih * 64 + lane) * 68;
        #pragma unroll
        for (int mt = 0; mt < 4; ++mt) {
            #pragma unroll
            for (int et = 0; et < 4; ++et)
                *(f32x4*)&dst[(mt * 4 + et) * 4] = oT[mt][et];
            dst[64 + mt] = l_[mt];
        }
    }
    __syncthreads();
    if (jh == 0) {
        const float* src = s_m + ((size_t)ih * 64 + lane) * 68;
        #pragma unroll
        for (int mt = 0; mt < 4; ++mt) {
            float lt = l_[mt] + src[64 + mt];
            float inv = (lt > 0.f) ? 1.f / lt : 0.f;
            int n = i0 + ih * 64 + mt * 16 + mr;
            #pragma unroll
            for (int et = 0; et < 4; ++et) {
                f32x4 o2 = *(const f32x4*)&src[(mt * 4 + et) * 4];
                float4 v = {(oT[mt][et][0] + o2[0]) * inv, (oT[mt][et][1] + o2[1]) * inv,
                            (oT[mt][et][2] + o2[2]) * inv, (oT[mt][et][3] + o2[3]) * inv};
                *(float4*)&out[((size_t)b * SEQ + n) * (HEADS * HDIM) + h * HDIM + et * 16 + q * 4] = v;
            }
        }
    }
}

extern "C" void kernel_launch(void* const* d_in, const int* in_sizes, int n_in,
                              void* d_out, int out_size, void* d_ws, size_t ws_size,
                              hipStream_t stream) {
    const float* hs   = (const float*)d_in[0];
    const int*   mask = (const int*)d_in[1];
    const float* Wt   = (const float*)d_in[2];
    const float* Wa   = (const float*)d_in[3];
    float* out = (float*)d_out;

    // workspace layout (38,928,384 B total):
    char* ws = (char*)d_ws;
    f16_t* t_f  = (f16_t*)ws;                  // 12.58 MB
    f16_t* tT_f = (f16_t*)(ws + 12582912);     // 12.58 MB
    f16_t* hs_f = (f16_t*)(ws + 25165824);     // 12.58 MB
    f16_t* w_f  = (f16_t*)(ws + 37748736);     //  1.18 MB  (fused Wa.Wt, fp16)

    prep_kernel<<<288 + 1024, 256, 0, stream>>>(
        (const float4*)hs, Wt, Wa, (f16x4*)hs_f, w_f);

    gemm_t<<<BATCH * HEADS * (SEQ / 128), 256, 0, stream>>>(hs_f, w_f, t_f, tT_f);

    attn_mfma<<<BATCH * HEADS * (SEQ / 128), 256, 0, stream>>>(
        t_f, tT_f, mask, out);
}